// Round 8
// baseline (394.214 us; speedup 1.0000x reference)
//
#include <hip/hip_runtime.h>

#define N_ROWS 65536
#define D 256
#define K 1024
#define DECAYF 0.99f
#define OMDF 0.01f
#define EPSF 1e-5f

typedef _Float16 f16;
typedef _Float16 f16x8 __attribute__((ext_vector_type(8)));
typedef float f32x16 __attribute__((ext_vector_type(16)));
typedef float f32x4 __attribute__((ext_vector_type(4)));

// ---------------- fused prep: zero dw/counts + codebook norms + hi/lo split ----------------
// wsB granule g (16B), g = stuff*64 + lane:
//   lane = h*32+l31 ; stuff = ((((ct*4+dk)*4+ks)*2+v)*8 + cfg)
//   content: fp16 (v=0 hi, v=1 lo) of cb[ct*256+cfg*32+l31][dk*64+ks*16+h*8 + e], e=0..7
__global__ __launch_bounds__(256) void prep_kernel(const float* __restrict__ cb,
                                                   float* __restrict__ cnorm,
                                                   char* __restrict__ wsB,
                                                   float* __restrict__ dw,
                                                   float* __restrict__ counts) {
    const int tid = threadIdx.x;
    const int bid = blockIdx.x;
    const int g = bid * 256 + tid;          // 0..65535
    *reinterpret_cast<float4*>(dw + (size_t)g * 4) = make_float4(0.f, 0.f, 0.f, 0.f);
    if (g < K) counts[g] = 0.f;
    {
        const int row = bid * 4 + (tid >> 6);
        const int lane = tid & 63;
        const float4 v = *reinterpret_cast<const float4*>(cb + (size_t)row * D + lane * 4);
        float s = v.x * v.x + v.y * v.y + v.z * v.z + v.w * v.w;
        #pragma unroll
        for (int m = 32; m; m >>= 1) s += __shfl_xor(s, m);
        if (lane == 0) cnorm[row] = s;
    }
    {
        const int l31 = g & 31;
        const int h   = (g >> 5) & 1;
        const int cfg = (g >> 6) & 7;
        const int v   = (g >> 9) & 1;
        const int ks  = (g >> 10) & 3;
        const int dk  = (g >> 12) & 3;
        const int ct  = (g >> 14) & 3;
        const int code = ct * 256 + cfg * 32 + l31;
        const int dim0 = dk * 64 + ks * 16 + h * 8;
        const float* src = cb + (size_t)code * D + dim0;
        f16 out[8];
        #pragma unroll
        for (int e = 0; e < 8; ++e) {
            const float f = src[e];
            const f16 hi = (f16)f;
            out[e] = v ? (f16)(f - (float)hi) : hi;
        }
        *reinterpret_cast<f16x8*>(wsB + (size_t)g * 16) = *reinterpret_cast<f16x8*>(out);
    }
}

// ---------------- MFMA argmin: A in LDS (staged once), B from L2, barrier-free loop ----------------
__global__ __launch_bounds__(256, 2) void argmin_mfma_kernel(
        const float* __restrict__ x, const char* __restrict__ wsB,
        const float* __restrict__ cnorm, int* __restrict__ idx_out,
        float* __restrict__ counts) {
    __shared__ char smem[67584];            // A: 64KB | Sv: 1KB @65536 | Si: 1KB @66560
    const int tid = threadIdx.x;
    const int cw = tid >> 6;                // wave = code-slice
    const int lane = tid & 63;
    const int l31 = lane & 31;
    const int h = lane >> 5;
    const int n0 = blockIdx.x * 64;

    // ---- stage A once: 64 rows x 256 dims -> hi/lo fp16 ----
    {
        const int s_row = tid >> 2;          // 0..63
        const int c4 = tid & 3;              // 64-dim chunk
        const float4* src = reinterpret_cast<const float4*>(
            x + (size_t)(n0 + s_row) * D + c4 * 64);
        char* rowbase = smem + s_row * 1024;
        const int sw = s_row & 7;
        #pragma unroll
        for (int j = 0; j < 8; ++j) {
            const float4 f0 = src[j * 2];
            const float4 f1 = src[j * 2 + 1];
            float f[8] = {f0.x, f0.y, f0.z, f0.w, f1.x, f1.y, f1.z, f1.w};
            f16 hi8[8], lo8[8];
            #pragma unroll
            for (int e = 0; e < 8; ++e) {
                hi8[e] = (f16)f[e];
                lo8[e] = (f16)(f[e] - (float)hi8[e]);
            }
            const int ph = (c4 * 8 + j) ^ sw;
            *reinterpret_cast<f16x8*>(rowbase + ph * 16)       = *reinterpret_cast<f16x8*>(hi8);
            *reinterpret_cast<f16x8*>(rowbase + 512 + ph * 16) = *reinterpret_cast<f16x8*>(lo8);
        }
    }
    __syncthreads();

    float bestv[2][16];
    int besti[2][16];
    #pragma unroll
    for (int rf = 0; rf < 2; ++rf)
        #pragma unroll
        for (int r = 0; r < 16; ++r) { bestv[rf][r] = 3.4e38f; besti[rf][r] = 0; }

    const int lane16 = lane * 16;
    const int arow0 = l31;
    const int arow1 = 32 + l31;
    char* abase0 = smem + arow0 * 1024;
    char* abase1 = smem + arow1 * 1024;
    const int asw0 = arow0 & 7;
    const int asw1 = arow1 & 7;
    const int cfg0 = cw * 2;

    #pragma unroll 1
    for (int ct = 0; ct < 4; ++ct) {
        f32x16 acc[2][2];
        #pragma unroll
        for (int rf = 0; rf < 2; ++rf)
            #pragma unroll
            for (int cf = 0; cf < 2; ++cf)
                #pragma unroll
                for (int r = 0; r < 16; ++r) acc[rf][cf][r] = 0.f;

        #pragma unroll
        for (int dk = 0; dk < 4; ++dk) {
            #pragma unroll
            for (int ks = 0; ks < 4; ++ks) {
                const int sbase = (((ct * 4 + dk) * 4 + ks) * 2) * 8;
                const f16x8 B00 = *reinterpret_cast<const f16x8*>(wsB + (size_t)(sbase + cfg0 + 0) * 1024 + lane16);
                const f16x8 B10 = *reinterpret_cast<const f16x8*>(wsB + (size_t)(sbase + cfg0 + 1) * 1024 + lane16);
                const f16x8 B01 = *reinterpret_cast<const f16x8*>(wsB + (size_t)(sbase + 8 + cfg0 + 0) * 1024 + lane16);
                const f16x8 B11 = *reinterpret_cast<const f16x8*>(wsB + (size_t)(sbase + 8 + cfg0 + 1) * 1024 + lane16);
                const int g = dk * 8 + ks * 2 + h;
                const f16x8 Ah0 = *reinterpret_cast<const f16x8*>(abase0 + ((g ^ asw0) * 16));
                const f16x8 Al0 = *reinterpret_cast<const f16x8*>(abase0 + 512 + ((g ^ asw0) * 16));
                const f16x8 Ah1 = *reinterpret_cast<const f16x8*>(abase1 + ((g ^ asw1) * 16));
                const f16x8 Al1 = *reinterpret_cast<const f16x8*>(abase1 + 512 + ((g ^ asw1) * 16));
                acc[0][0] = __builtin_amdgcn_mfma_f32_32x32x16_f16(Ah0, B00, acc[0][0], 0, 0, 0);
                acc[0][0] = __builtin_amdgcn_mfma_f32_32x32x16_f16(Ah0, B01, acc[0][0], 0, 0, 0);
                acc[0][0] = __builtin_amdgcn_mfma_f32_32x32x16_f16(Al0, B00, acc[0][0], 0, 0, 0);
                acc[0][1] = __builtin_amdgcn_mfma_f32_32x32x16_f16(Ah0, B10, acc[0][1], 0, 0, 0);
                acc[0][1] = __builtin_amdgcn_mfma_f32_32x32x16_f16(Ah0, B11, acc[0][1], 0, 0, 0);
                acc[0][1] = __builtin_amdgcn_mfma_f32_32x32x16_f16(Al0, B10, acc[0][1], 0, 0, 0);
                acc[1][0] = __builtin_amdgcn_mfma_f32_32x32x16_f16(Ah1, B00, acc[1][0], 0, 0, 0);
                acc[1][0] = __builtin_amdgcn_mfma_f32_32x32x16_f16(Ah1, B01, acc[1][0], 0, 0, 0);
                acc[1][0] = __builtin_amdgcn_mfma_f32_32x32x16_f16(Al1, B00, acc[1][0], 0, 0, 0);
                acc[1][1] = __builtin_amdgcn_mfma_f32_32x32x16_f16(Ah1, B10, acc[1][1], 0, 0, 0);
                acc[1][1] = __builtin_amdgcn_mfma_f32_32x32x16_f16(Ah1, B11, acc[1][1], 0, 0, 0);
                acc[1][1] = __builtin_amdgcn_mfma_f32_32x32x16_f16(Al1, B10, acc[1][1], 0, 0, 0);
            }
        }
        const int code0 = ct * 256 + cw * 64 + l31;
        const int code1 = code0 + 32;
        const float cn0 = cnorm[code0];
        const float cn1 = cnorm[code1];
        #pragma unroll
        for (int rf = 0; rf < 2; ++rf)
            #pragma unroll
            for (int r = 0; r < 16; ++r) {
                const float d0 = cn0 - 2.f * acc[rf][0][r];
                const float d1 = cn1 - 2.f * acc[rf][1][r];
                float dv = d0; int db = code0;
                if (d1 < dv) { dv = d1; db = code1; }
                if (dv < bestv[rf][r]) { bestv[rf][r] = dv; besti[rf][r] = db; }
            }
    }
    #pragma unroll
    for (int rf = 0; rf < 2; ++rf)
        #pragma unroll
        for (int r = 0; r < 16; ++r) {
            float v = bestv[rf][r];
            int b = besti[rf][r];
            #pragma unroll
            for (int m = 16; m; m >>= 1) {
                const float ov = __shfl_xor(v, m);
                const int ob = __shfl_xor(b, m);
                if (ov < v || (ov == v && ob < b)) { v = ov; b = ob; }
            }
            bestv[rf][r] = v; besti[rf][r] = b;
        }
    __syncthreads();
    float* Sv = reinterpret_cast<float*>(smem + 65536);       // [4][64] floats (1KB)
    int*   Si = reinterpret_cast<int*>(smem + 66560);         // [4][64] ints  (1KB)
    if (l31 == 0) {
        #pragma unroll
        for (int rf = 0; rf < 2; ++rf)
            #pragma unroll
            for (int r = 0; r < 16; ++r) {
                const int row = rf * 32 + (r & 3) + 8 * (r >> 2) + 4 * h;
                Sv[cw * 64 + row] = bestv[rf][r];
                Si[cw * 64 + row] = besti[rf][r];
            }
    }
    __syncthreads();
    if (tid < 64) {
        float v = Sv[tid];
        int b = Si[tid];
        #pragma unroll
        for (int w = 1; w < 4; ++w) {
            const float ov = Sv[w * 64 + tid];
            const int ob = Si[w * 64 + tid];
            if (ov < v || (ov == v && ob < b)) { v = ov; b = ob; }
        }
        idx_out[n0 + tid] = b;
        atomicAdd(&counts[b], 1.0f);
    }
}

// ---------------- quantized gather (nontemporal stores) ----------------
__global__ __launch_bounds__(256) void quant_kernel(const float* __restrict__ cb,
                                                    const int* __restrict__ idx,
                                                    float* __restrict__ quant) {
    const int n = blockIdx.x * 4 + (threadIdx.x >> 6);
    const int lane = threadIdx.x & 63;
    const int i = idx[n];
    const f32x4 c = *reinterpret_cast<const f32x4*>(cb + (size_t)i * D + lane * 4);
    __builtin_nontemporal_store(c, reinterpret_cast<f32x4*>(quant + (size_t)n * D + lane * 4));
}

// ---------------- one-hot encodings (nontemporal stores) ----------------
__global__ __launch_bounds__(256) void enc_kernel(const int* __restrict__ idx,
                                                  float* __restrict__ enc) {
    const int total = N_ROWS * (K / 4);
    for (int g = blockIdx.x * blockDim.x + threadIdx.x; g < total;
         g += gridDim.x * blockDim.x) {
        const int n = g >> 8;
        const int k0 = (g & 255) * 4;
        const int i = idx[n];
        f32x4 v;
        v[0] = (k0 == i) ? 1.f : 0.f;
        v[1] = (k0 + 1 == i) ? 1.f : 0.f;
        v[2] = (k0 + 2 == i) ? 1.f : 0.f;
        v[3] = (k0 + 3 == i) ? 1.f : 0.f;
        __builtin_nontemporal_store(v, reinterpret_cast<f32x4*>(enc + (size_t)g * 4));
    }
}

// ---------------- cs EMA + Laplace + exclusive scan (wave-scan) ----------------
__global__ __launch_bounds__(1024) void cs_scan_kernel(const float* __restrict__ ema_cs,
                                                       const float* __restrict__ counts,
                                                       float* __restrict__ cs_out,
                                                       int* __restrict__ cursor) {
    __shared__ float wsum[16];
    __shared__ int wisum[16];
    __shared__ float n_sh;
    const int k = threadIdx.x;
    const int wid = k >> 6;
    const int lane = k & 63;
    const float cnt = counts[k];
    const float c = ema_cs[k] * DECAYF + OMDF * cnt;
    const int ic = (int)cnt;
    int v = ic;
    #pragma unroll
    for (int d = 1; d < 64; d <<= 1) {
        const int t = __shfl_up(v, d);
        if (lane >= d) v += t;
    }
    float s = c;
    #pragma unroll
    for (int m = 32; m; m >>= 1) s += __shfl_xor(s, m);
    if (lane == 63) wisum[wid] = v;
    if (lane == 0) wsum[wid] = s;
    __syncthreads();
    if (k == 0) {
        float n = 0.f;
        for (int w = 0; w < 16; ++w) n += wsum[w];
        n_sh = n;
    }
    if (wid == 0 && lane < 16) {
        int wv = wisum[lane];
        #pragma unroll
        for (int d = 1; d < 16; d <<= 1) {
            const int t = __shfl_up(wv, d);
            if (lane >= d) wv += t;
        }
        wisum[lane] = wv;
    }
    __syncthreads();
    const float n = n_sh;
    cs_out[k] = (c + EPSF) / (n + c * EPSF) * n;
    const int wbase = (wid == 0) ? 0 : wisum[wid - 1];
    cursor[k] = wbase + v - ic;
}

// ---------------- scatter rows by code, block-aggregated ----------------
__global__ __launch_bounds__(256) void scatter_kernel(const int* __restrict__ idx,
                                                      int* __restrict__ cursor,
                                                      int* __restrict__ rowlist,
                                                      int* __restrict__ codelist) {
    __shared__ int hist[1024];
    const int tid = threadIdx.x;
    #pragma unroll
    for (int j = 0; j < 4; ++j) hist[tid + j * 256] = 0;
    __syncthreads();
    const int n = blockIdx.x * 256 + tid;
    const int i = idx[n];
    atomicAdd(&hist[i], 1);
    __syncthreads();
    #pragma unroll
    for (int j = 0; j < 4; ++j) {
        const int k = tid + j * 256;
        const int c = hist[k];
        hist[k] = (c > 0) ? atomicAdd(&cursor[k], c) : 0;
    }
    __syncthreads();
    const int pos = atomicAdd(&hist[i], 1);
    rowlist[pos] = n;
    codelist[pos] = i;
}

// ---------------- balanced segmented sum over sorted rowlist ----------------
__global__ __launch_bounds__(256) void chunk_sum_kernel(const float* __restrict__ x,
                                                        const int* __restrict__ rowlist,
                                                        const int* __restrict__ codelist,
                                                        float* __restrict__ dw) {
    const int wave = threadIdx.x >> 6;
    const int lane = threadIdx.x & 63;
    const int p0 = blockIdx.x * 32 + wave * 8;
    int rows[8], codes[8];
    #pragma unroll
    for (int j = 0; j < 8; ++j) {
        rows[j] = rowlist[p0 + j];
        codes[j] = codelist[p0 + j];
    }
    float4 v[8];
    #pragma unroll
    for (int j = 0; j < 8; ++j)
        v[j] = *reinterpret_cast<const float4*>(x + (size_t)rows[j] * D + lane * 4);
    float4 s = v[0];
    int cur = codes[0];
    #pragma unroll
    for (int j = 1; j < 8; ++j) {
        if (codes[j] != cur) {
            float* dst = dw + (size_t)cur * D + lane * 4;
            atomicAdd(dst + 0, s.x); atomicAdd(dst + 1, s.y);
            atomicAdd(dst + 2, s.z); atomicAdd(dst + 3, s.w);
            cur = codes[j];
            s = v[j];
        } else {
            s.x += v[j].x; s.y += v[j].y; s.z += v[j].z; s.w += v[j].w;
        }
    }
    float* dst = dw + (size_t)cur * D + lane * 4;
    atomicAdd(dst + 0, s.x); atomicAdd(dst + 1, s.y);
    atomicAdd(dst + 2, s.z); atomicAdd(dst + 3, s.w);
}

// ---------------- ema_w + new codebook ----------------
__global__ __launch_bounds__(256) void ema_kernel(const float* __restrict__ ema_w,
                                                  const float* __restrict__ dw,
                                                  const float* __restrict__ cs,
                                                  float* __restrict__ w_out,
                                                  float* __restrict__ cb_out) {
    const int e4 = blockIdx.x * blockDim.x + threadIdx.x;
    const int k = e4 >> 6;
    const float csk = cs[k];
    const float4 w = *reinterpret_cast<const float4*>(ema_w + (size_t)e4 * 4);
    const float4 d = *reinterpret_cast<const float4*>(dw + (size_t)e4 * 4);
    float4 nw, nc;
    nw.x = w.x * DECAYF + OMDF * d.x;
    nw.y = w.y * DECAYF + OMDF * d.y;
    nw.z = w.z * DECAYF + OMDF * d.z;
    nw.w = w.w * DECAYF + OMDF * d.w;
    nc.x = nw.x / csk; nc.y = nw.y / csk; nc.z = nw.z / csk; nc.w = nw.w / csk;
    *reinterpret_cast<float4*>(w_out + (size_t)e4 * 4) = nw;
    *reinterpret_cast<float4*>(cb_out + (size_t)e4 * 4) = nc;
}

extern "C" void kernel_launch(void* const* d_in, const int* in_sizes, int n_in,
                              void* d_out, int out_size, void* d_ws, size_t ws_size,
                              hipStream_t stream) {
    (void)in_sizes; (void)n_in; (void)out_size; (void)ws_size;
    const float* x      = (const float*)d_in[0];
    const float* cb     = (const float*)d_in[1];
    const float* ema_w  = (const float*)d_in[2];
    const float* ema_cs = (const float*)d_in[3];

    float* out    = (float*)d_out;
    float* quant  = out;
    float* enc    = quant + 16777216;
    float* cs_out = enc + 67108864;
    float* w_out  = cs_out + 1024;
    float* cb_out = w_out + 262144;

    float* ws       = (float*)d_ws;
    float* counts   = ws;                          // 1024 f
    float* dw       = ws + 1024;                   // 262144 f
    float* cnorm    = ws + 263168;                 // 1024 f
    int*   cursor   = (int*)(ws + 264192);         // 1024 i
    int*   idx      = (int*)(ws + 265216);         // 65536 i
    int*   rowlist  = (int*)(ws + 330752);         // 65536 i
    int*   codelist = (int*)(ws + 396288);         // 65536 i
    char*  wsB      = (char*)(ws + 461824);        // 1 MiB, 16B aligned

    prep_kernel<<<256, 256, 0, stream>>>(cb, cnorm, wsB, dw, counts);
    argmin_mfma_kernel<<<N_ROWS / 64, 256, 0, stream>>>(x, wsB, cnorm, idx, counts);
    quant_kernel<<<N_ROWS / 4, 256, 0, stream>>>(cb, idx, quant);
    enc_kernel<<<2048, 256, 0, stream>>>(idx, enc);
    cs_scan_kernel<<<1, 1024, 0, stream>>>(ema_cs, counts, cs_out, cursor);
    scatter_kernel<<<N_ROWS / 256, 256, 0, stream>>>(idx, cursor, rowlist, codelist);
    chunk_sum_kernel<<<2048, 256, 0, stream>>>(x, rowlist, codelist, dw);
    ema_kernel<<<65536 / 256, 256, 0, stream>>>(ema_w, dw, cs_out, w_out, cb_out);
}